// Round 1
// baseline (597.679 us; speedup 1.0000x reference)
//
#include <hip/hip_runtime.h>
#include <cstdint>
#include <cstddef>

using u16 = unsigned short;
using u32 = unsigned int;

// ---------- dtype helpers (manual bf16 so we don't depend on header semantics) ----------
__device__ __forceinline__ float bf2f(u16 h) { return __uint_as_float(((u32)h) << 16); }
__device__ __forceinline__ u16 f2bf(float f) {
    u32 u = __float_as_uint(f);
    u += 0x7FFFu + ((u >> 16) & 1u);   // RNE
    return (u16)(u >> 16);
}
__device__ __forceinline__ float to_f(float v) { return v; }
__device__ __forceinline__ float to_f(u16 v) { return bf2f(v); }

template <typename T> struct OutCvt;
template <> struct OutCvt<float> { static __device__ __forceinline__ float cvt(float v) { return v; } };
template <> struct OutCvt<u16>   { static __device__ __forceinline__ u16   cvt(float v) { return f2bf(v); } };

// load 8 consecutive elements as f32 (16B-aligned addresses in all call sites)
__device__ __forceinline__ void load8(const float* p, float* v) {
    float4 a = ((const float4*)p)[0];
    float4 b = ((const float4*)p)[1];
    v[0]=a.x; v[1]=a.y; v[2]=a.z; v[3]=a.w;
    v[4]=b.x; v[5]=b.y; v[6]=b.z; v[7]=b.w;
}
__device__ __forceinline__ void load8(const u16* p, float* v) {
    uint4 u = *(const uint4*)p;
    v[0]=__uint_as_float(u.x << 16); v[1]=__uint_as_float(u.x & 0xFFFF0000u);
    v[2]=__uint_as_float(u.y << 16); v[3]=__uint_as_float(u.y & 0xFFFF0000u);
    v[4]=__uint_as_float(u.z << 16); v[5]=__uint_as_float(u.z & 0xFFFF0000u);
    v[6]=__uint_as_float(u.w << 16); v[7]=__uint_as_float(u.w & 0xFFFF0000u);
}

// ---------- 0. runtime dtype detection ----------
// flags[0]: 1 = float tensors are bf16, 0 = f32.  flags[1]: edge-index stride in
// 32-bit words (1 = int32, 2 = int64 little-endian low word).
__global__ __launch_bounds__(64) void detect_kernel(const u16* xraw, const u32* idxraw, int* flags) {
    if (threadIdx.x == 0 && blockIdx.x == 0) {
        int big = 0;
        for (int i = 0; i < 256; ++i) {
            int ex = (xraw[i] >> 7) & 0xFF;
            if (ex >= 0x90) big++;          // |v| >= 2^17 -> impossible for bf16 N(0,1) data
        }
        flags[0] = (big == 0) ? 1 : 0;
        int nz = 0;
        for (int i = 1; i < 256; i += 2) if (idxraw[i] != 0u) nz++;
        flags[1] = (nz == 0) ? 2 : 1;       // all-high-words-zero -> int64
    }
}

// ---------- 1. CSR build ----------
__global__ __launch_bounds__(256) void hist_kernel(const int* idx, const int* __restrict__ flags,
                                                   int* cnt, int E) {
    const int stride = flags[1];
    int e = blockIdx.x * blockDim.x + threadIdx.x;
    const int step = gridDim.x * blockDim.x;
    for (; e < E; e += step) {
        int d = idx[(size_t)(E + e) * stride];
        atomicAdd(&cnt[d], 1);
    }
}

#define SCAN_THREADS 1024
__global__ __launch_bounds__(SCAN_THREADS) void scan_kernel(const int* __restrict__ cnt,
                                                            int* row_ptr, int* cursor, int n) {
    __shared__ int sums[SCAN_THREADS];
    const int tid = threadIdx.x;
    const int chunk = (n + SCAN_THREADS - 1) / SCAN_THREADS;
    const int begin = tid * chunk;
    const int end = min(begin + chunk, n);
    int s = 0;
    for (int i = begin; i < end; ++i) s += cnt[i];
    sums[tid] = s;
    __syncthreads();
    for (int off = 1; off < SCAN_THREADS; off <<= 1) {   // in-place Hillis-Steele (inclusive)
        int v = (tid >= off) ? sums[tid - off] : 0;
        __syncthreads();
        sums[tid] += v;
        __syncthreads();
    }
    int run = (tid == 0) ? 0 : sums[tid - 1];            // exclusive offset for this chunk
    for (int i = begin; i < end; ++i) {
        row_ptr[i] = run; cursor[i] = run; run += cnt[i];
    }
    if (end == n) row_ptr[n] = run;                      // total (benign multi-write, same value)
}

__global__ __launch_bounds__(256) void scatter_kernel(const int* idx, const int* __restrict__ flags,
                                                      int* cursor, int* ssrc, int E) {
    const int stride = flags[1];
    int e = blockIdx.x * blockDim.x + threadIdx.x;
    const int step = gridDim.x * blockDim.x;
    for (; e < E; e += step) {
        int s = idx[(size_t)e * stride];
        int d = idx[(size_t)(E + e) * stride];
        int pos = atomicAdd(&cursor[d], 1);
        ssrc[pos] = s;
    }
}

// ---------- 2. mean aggregation (wave per node, 8 f32 per lane) ----------
// mode >= 0: run only if flags[0]==mode; mode < 0: always run.
template <typename T, int D>
__global__ __launch_bounds__(256) void agg_kernel(const T* __restrict__ feat,
                                                  const int* __restrict__ row_ptr,
                                                  const int* __restrict__ ssrc,
                                                  float* __restrict__ out,
                                                  const int* __restrict__ flags, int n, int mode) {
    if (mode >= 0 && flags[0] != mode) return;
    constexpr int LPN = D / 8;      // lanes per node-row
    constexpr int G = 64 / LPN;     // edges in flight per wave
    const int lane = threadIdx.x & 63;
    const int wid = (blockIdx.x * blockDim.x + threadIdx.x) >> 6;
    const int nw = (gridDim.x * blockDim.x) >> 6;
    const int g = lane / LPN;       // edge slot
    const int q = lane % LPN;       // feature octet
    for (int i = wid; i < n; i += nw) {
        const int rb = row_ptr[i], re = row_ptr[i + 1];
        float acc[8];
        #pragma unroll
        for (int k = 0; k < 8; ++k) acc[k] = 0.f;
        for (int e = rb + g; e < re; e += G) {
            int s = ssrc[e];
            float v[8];
            load8(feat + (size_t)s * D + q * 8, v);
            #pragma unroll
            for (int k = 0; k < 8; ++k) acc[k] += v[k];
        }
        #pragma unroll
        for (int m = LPN; m < 64; m <<= 1) {
            #pragma unroll
            for (int k = 0; k < 8; ++k) acc[k] += __shfl_xor(acc[k], m, 64);
        }
        if (g == 0) {
            float inv = 1.0f / (float)max(re - rb, 1);
            float4 v0 = make_float4(acc[0]*inv, acc[1]*inv, acc[2]*inv, acc[3]*inv);
            float4 v1 = make_float4(acc[4]*inv, acc[5]*inv, acc[6]*inv, acc[7]*inv);
            float4* dst = (float4*)(out + (size_t)i * D + q * 8);
            dst[0] = v0; dst[1] = v1;
        }
    }
}

// ---------- 3. layer-1 fused: h1 = relu(A1@W1l.T + b1 + x@W1r.T); z2 = h1@W2l.T; r2 = b2 + h1@W2r.T
// Wave per node, lane = channel, weight rows in registers, readlane broadcast for the contraction.
template <typename T>
__global__ __launch_bounds__(256, 2) void layer1_kernel(
    const float* __restrict__ A1, const T* __restrict__ x,
    const T* __restrict__ W1l, const T* __restrict__ b1,
    const T* __restrict__ W1r, const T* __restrict__ W2l,
    const T* __restrict__ b2, const T* __restrict__ W2r,
    float* __restrict__ z2, float* __restrict__ r2,
    const int* __restrict__ flags, int n, int mode)
{
    if (flags[0] != mode) return;
    const int lane = threadIdx.x & 63;
    const int wid = (blockIdx.x * blockDim.x + threadIdx.x) >> 6;
    const int nw = (gridDim.x * blockDim.x) >> 6;

    float wl[64], wr[64], w2[64];
    #pragma unroll
    for (int k8 = 0; k8 < 8; ++k8) {
        load8(W1l + (size_t)lane * 64 + k8 * 8, &wl[k8 * 8]);
        load8(W1r + (size_t)lane * 64 + k8 * 8, &wr[k8 * 8]);
    }
    const T* w2src = (lane < 32) ? (W2l + (size_t)lane * 64) : (W2r + (size_t)(lane - 32) * 64);
    #pragma unroll
    for (int k8 = 0; k8 < 8; ++k8) load8(w2src + k8 * 8, &w2[k8 * 8]);
    const float b1c = to_f(b1[lane]);
    const float zinit = (lane < 32) ? 0.0f : to_f(b2[lane - 32]);

    for (int i = wid; i < n; i += nw) {
        const float* arow = A1 + (size_t)i * 64;
        const T* xrow = x + (size_t)i * 64;
        float acc = b1c;
        #pragma unroll
        for (int k8 = 0; k8 < 8; ++k8) {
            float av[8], xv[8];
            load8(arow + k8 * 8, av);       // wave-uniform address -> broadcast
            load8(xrow + k8 * 8, xv);
            #pragma unroll
            for (int k = 0; k < 8; ++k)
                acc += av[k] * wl[k8 * 8 + k] + xv[k] * wr[k8 * 8 + k];
        }
        const float h1 = fmaxf(acc, 0.0f);
        float accz = zinit;
        #pragma unroll
        for (int c = 0; c < 64; ++c) {
            float hc = __int_as_float(__builtin_amdgcn_readlane(__float_as_int(h1), c));
            accz = fmaf(hc, w2[c], accz);
        }
        if (lane < 32) z2[(size_t)i * 32 + lane] = accz;
        else           r2[(size_t)i * 32 + (lane - 32)] = accz;
    }
}

// ---------- 4. final: h2 = relu(A2 + r2); out = h2 . wlin + blin  (32 lanes per node) ----------
template <typename T, typename TOut>
__global__ __launch_bounds__(256) void final_kernel(
    const float* __restrict__ A2, const float* __restrict__ r2,
    const T* __restrict__ Wlin, const T* __restrict__ blin,
    TOut* __restrict__ out, const int* __restrict__ flags, int n, int mode)
{
    if (flags[0] != mode) return;
    const int t = blockIdx.x * blockDim.x + threadIdx.x;
    const int total = gridDim.x * blockDim.x;
    const int j = t & 31;
    const float wj = to_f(Wlin[j]);
    const float bl = to_f(blin[0]);
    for (int i = t >> 5; i < n; i += (total >> 5)) {
        size_t o = (size_t)i * 32 + j;
        float v = fmaxf(A2[o] + r2[o], 0.0f) * wj;
        #pragma unroll
        for (int m = 1; m < 32; m <<= 1) v += __shfl_xor(v, m, 64);   // stays within 32-lane halves
        if (j == 0) out[i] = OutCvt<TOut>::cvt(v + bl);
    }
}

// ---------- host ----------
extern "C" void kernel_launch(void* const* d_in, const int* in_sizes, int n_in,
                              void* d_out, int out_size, void* d_ws, size_t ws_size,
                              hipStream_t stream) {
    (void)n_in; (void)out_size; (void)ws_size;
    const int N = in_sizes[0] / 64;
    const int E = in_sizes[1] / 2;

    char* ws = (char*)d_ws;
    size_t off = 0;
    auto alloc = [&](size_t bytes) -> void* {
        void* p = ws + off;
        off += (bytes + 255) & ~(size_t)255;
        return p;
    };
    int*   flags   = (int*)alloc(16);
    int*   cnt     = (int*)alloc((size_t)N * 4);
    int*   cursor  = (int*)alloc((size_t)N * 4);
    int*   row_ptr = (int*)alloc(((size_t)N + 1) * 4);
    int*   ssrc    = (int*)alloc((size_t)E * 4);
    float* A1      = (float*)alloc((size_t)N * 64 * 4);
    float* A2      = (float*)alloc((size_t)N * 32 * 4);
    float* z2      = (float*)alloc((size_t)N * 32 * 4);
    float* r2      = (float*)alloc((size_t)N * 32 * 4);

    const int* idx = (const int*)d_in[1];

    detect_kernel<<<1, 64, 0, stream>>>((const u16*)d_in[0], (const u32*)d_in[1], flags);
    hipMemsetAsync(cnt, 0, (size_t)N * 4, stream);
    hist_kernel<<<512, 256, 0, stream>>>(idx, flags, cnt, E);
    scan_kernel<<<1, SCAN_THREADS, 0, stream>>>(cnt, row_ptr, cursor, N);
    scatter_kernel<<<512, 256, 0, stream>>>(idx, flags, cursor, ssrc, E);

    // layer-1 aggregation of raw x (mode-guarded dual variants)
    agg_kernel<u16, 64><<<2048, 256, 0, stream>>>((const u16*)d_in[0], row_ptr, ssrc, A1, flags, N, 1);
    agg_kernel<float, 64><<<2048, 256, 0, stream>>>((const float*)d_in[0], row_ptr, ssrc, A1, flags, N, 0);

    layer1_kernel<u16><<<1024, 256, 0, stream>>>(A1, (const u16*)d_in[0],
        (const u16*)d_in[2], (const u16*)d_in[3], (const u16*)d_in[4],
        (const u16*)d_in[5], (const u16*)d_in[6], (const u16*)d_in[7],
        z2, r2, flags, N, 1);
    layer1_kernel<float><<<1024, 256, 0, stream>>>(A1, (const float*)d_in[0],
        (const float*)d_in[2], (const float*)d_in[3], (const float*)d_in[4],
        (const float*)d_in[5], (const float*)d_in[6], (const float*)d_in[7],
        z2, r2, flags, N, 0);

    // layer-2 aggregation of z2 (f32, dtype-independent -> single launch)
    agg_kernel<float, 32><<<2048, 256, 0, stream>>>(z2, row_ptr, ssrc, A2, flags, N, -1);

    final_kernel<u16, u16><<<1024, 256, 0, stream>>>(A2, r2, (const u16*)d_in[8], (const u16*)d_in[9],
                                                     (u16*)d_out, flags, N, 1);
    final_kernel<float, float><<<1024, 256, 0, stream>>>(A2, r2, (const float*)d_in[8], (const float*)d_in[9],
                                                         (float*)d_out, flags, N, 0);
}

// Round 2
// 415.939 us; speedup vs baseline: 1.4369x; 1.4369x over previous
//
#include <hip/hip_runtime.h>
#include <cstdint>
#include <cstddef>

using u16 = unsigned short;
using u32 = unsigned int;

// ---------- dtype helpers ----------
__device__ __forceinline__ float bf2f(u16 h) { return __uint_as_float(((u32)h) << 16); }
__device__ __forceinline__ u16 f2bf(float f) {
    u32 u = __float_as_uint(f);
    u += 0x7FFFu + ((u >> 16) & 1u);   // RNE
    return (u16)(u >> 16);
}
__device__ __forceinline__ float to_f(float v) { return v; }
__device__ __forceinline__ float to_f(u16 v) { return bf2f(v); }

template <typename T> struct OutCvt;
template <> struct OutCvt<float> { static __device__ __forceinline__ float cvt(float v) { return v; } };
template <> struct OutCvt<u16>   { static __device__ __forceinline__ u16   cvt(float v) { return f2bf(v); } };

// load 8 consecutive elements as f32 (16B-aligned addresses at all call sites)
__device__ __forceinline__ void load8(const float* p, float* v) {
    float4 a = ((const float4*)p)[0];
    float4 b = ((const float4*)p)[1];
    v[0]=a.x; v[1]=a.y; v[2]=a.z; v[3]=a.w;
    v[4]=b.x; v[5]=b.y; v[6]=b.z; v[7]=b.w;
}
__device__ __forceinline__ void load8(const u16* p, float* v) {
    uint4 u = *(const uint4*)p;
    v[0]=__uint_as_float(u.x << 16); v[1]=__uint_as_float(u.x & 0xFFFF0000u);
    v[2]=__uint_as_float(u.y << 16); v[3]=__uint_as_float(u.y & 0xFFFF0000u);
    v[4]=__uint_as_float(u.z << 16); v[5]=__uint_as_float(u.z & 0xFFFF0000u);
    v[6]=__uint_as_float(u.w << 16); v[7]=__uint_as_float(u.w & 0xFFFF0000u);
}

// ---------- 0. runtime dtype detection ----------
// flags[0]: 1 = float tensors are bf16, 0 = f32.  flags[1]: edge-index stride
// in 32-bit words (1 = int32, 2 = int64 low word).
__global__ __launch_bounds__(64) void detect_kernel(const u16* xraw, const u32* idxraw, int* flags) {
    if (threadIdx.x == 0 && blockIdx.x == 0) {
        int big = 0;
        for (int i = 0; i < 256; ++i) {
            int ex = (xraw[i] >> 7) & 0xFF;
            if (ex >= 0x90) big++;          // |v| >= 2^17 impossible for bf16 N(0,1) data
        }
        flags[0] = (big == 0) ? 1 : 0;
        int nz = 0;
        for (int i = 1; i < 256; i += 2) if (idxraw[i] != 0u) nz++;
        flags[1] = (nz == 0) ? 2 : 1;       // all-high-words-zero -> int64
    }
}

// ---------- 1. CSR build (atomic decoupled from the scatter store) ----------
__global__ __launch_bounds__(256) void hist_kernel(const int* idx, const int* __restrict__ flags,
                                                   int* cnt, int* within, int E) {
    const int e = blockIdx.x * blockDim.x + threadIdx.x;
    if (e >= E) return;
    const int stride = flags[1];
    const int d = idx[(size_t)(E + e) * stride];
    within[e] = atomicAdd(&cnt[d], 1);      // coalesced result store; any permutation is valid
}

#define SCAN_THREADS 1024
__global__ __launch_bounds__(SCAN_THREADS) void scan_kernel(const int* __restrict__ cnt,
                                                            int* row_ptr, int n) {
    __shared__ int sums[SCAN_THREADS];
    const int tid = threadIdx.x;
    const int chunk = (n + SCAN_THREADS - 1) / SCAN_THREADS;
    const int begin = tid * chunk;
    const int end = min(begin + chunk, n);
    int s = 0;
    for (int i = begin; i < end; ++i) s += cnt[i];
    sums[tid] = s;
    __syncthreads();
    for (int off = 1; off < SCAN_THREADS; off <<= 1) {   // Hillis-Steele inclusive
        int v = (tid >= off) ? sums[tid - off] : 0;
        __syncthreads();
        sums[tid] += v;
        __syncthreads();
    }
    int run = (tid == 0) ? 0 : sums[tid - 1];
    for (int i = begin; i < end; ++i) { row_ptr[i] = run; run += cnt[i]; }
    if (end == n) row_ptr[n] = run;
}

// atomic-free: position = row_ptr[dst] + within[e]; store is fire-and-forget
__global__ __launch_bounds__(256) void scatter_kernel(const int* idx, const int* __restrict__ flags,
                                                      const int* __restrict__ row_ptr,
                                                      const int* __restrict__ within,
                                                      int* ssrc, int E) {
    const int e = blockIdx.x * blockDim.x + threadIdx.x;
    if (e >= E) return;
    const int stride = flags[1];
    const int s = idx[(size_t)e * stride];
    const int d = idx[(size_t)(E + e) * stride];
    ssrc[row_ptr[d] + within[e]] = s;
}

// ---------- 2. layer-1 mean aggregation (wave per node, 8 f32 per lane) ----------
template <typename T, int D>
__global__ __launch_bounds__(256) void agg_kernel(const T* __restrict__ feat,
                                                  const int* __restrict__ row_ptr,
                                                  const int* __restrict__ ssrc,
                                                  float* __restrict__ out,
                                                  const int* __restrict__ flags, int n, int mode) {
    if (mode >= 0 && flags[0] != mode) return;
    constexpr int LPN = D / 8;      // lanes per node-row
    constexpr int G = 64 / LPN;     // edges in flight per wave
    const int lane = threadIdx.x & 63;
    const int wid = (blockIdx.x * blockDim.x + threadIdx.x) >> 6;
    const int nw = (gridDim.x * blockDim.x) >> 6;
    const int g = lane / LPN;       // edge slot
    const int q = lane % LPN;       // feature octet
    for (int i = wid; i < n; i += nw) {
        const int rb = row_ptr[i], re = row_ptr[i + 1];
        float acc[8];
        #pragma unroll
        for (int k = 0; k < 8; ++k) acc[k] = 0.f;
        for (int e = rb + g; e < re; e += G) {
            int s = ssrc[e];
            float v[8];
            load8(feat + (size_t)s * D + q * 8, v);
            #pragma unroll
            for (int k = 0; k < 8; ++k) acc[k] += v[k];
        }
        #pragma unroll
        for (int m = LPN; m < 64; m <<= 1) {
            #pragma unroll
            for (int k = 0; k < 8; ++k) acc[k] += __shfl_xor(acc[k], m, 64);
        }
        if (g == 0) {
            float inv = 1.0f / (float)max(re - rb, 1);
            float4 v0 = make_float4(acc[0]*inv, acc[1]*inv, acc[2]*inv, acc[3]*inv);
            float4 v1 = make_float4(acc[4]*inv, acc[5]*inv, acc[6]*inv, acc[7]*inv);
            float4* dst = (float4*)(out + (size_t)i * D + q * 8);
            dst[0] = v0; dst[1] = v1;
        }
    }
}

// ---------- 3. layer-1 fused transform:
// h1 = relu(A1@W1l.T + b1 + x@W1r.T); z2 = bf16(h1@W2l.T); r2 = b2 + h1@W2r.T
template <typename T>
__global__ __launch_bounds__(256, 2) void layer1_kernel(
    const float* __restrict__ A1, const T* __restrict__ x,
    const T* __restrict__ W1l, const T* __restrict__ b1,
    const T* __restrict__ W1r, const T* __restrict__ W2l,
    const T* __restrict__ b2, const T* __restrict__ W2r,
    u16* __restrict__ z2, float* __restrict__ r2,
    const int* __restrict__ flags, int n, int mode)
{
    if (flags[0] != mode) return;
    const int lane = threadIdx.x & 63;
    const int wid = (blockIdx.x * blockDim.x + threadIdx.x) >> 6;
    const int nw = (gridDim.x * blockDim.x) >> 6;

    float wl[64], wr[64], w2[64];
    #pragma unroll
    for (int k8 = 0; k8 < 8; ++k8) {
        load8(W1l + (size_t)lane * 64 + k8 * 8, &wl[k8 * 8]);
        load8(W1r + (size_t)lane * 64 + k8 * 8, &wr[k8 * 8]);
    }
    const T* w2src = (lane < 32) ? (W2l + (size_t)lane * 64) : (W2r + (size_t)(lane - 32) * 64);
    #pragma unroll
    for (int k8 = 0; k8 < 8; ++k8) load8(w2src + k8 * 8, &w2[k8 * 8]);
    const float b1c = to_f(b1[lane]);
    const float zinit = (lane < 32) ? 0.0f : to_f(b2[lane - 32]);

    for (int i = wid; i < n; i += nw) {
        const float* arow = A1 + (size_t)i * 64;
        const T* xrow = x + (size_t)i * 64;
        float acc = b1c;
        #pragma unroll
        for (int k8 = 0; k8 < 8; ++k8) {
            float av[8], xv[8];
            load8(arow + k8 * 8, av);
            load8(xrow + k8 * 8, xv);
            #pragma unroll
            for (int k = 0; k < 8; ++k)
                acc += av[k] * wl[k8 * 8 + k] + xv[k] * wr[k8 * 8 + k];
        }
        const float h1 = fmaxf(acc, 0.0f);
        float accz = zinit;
        #pragma unroll
        for (int c = 0; c < 64; ++c) {
            float hc = __int_as_float(__builtin_amdgcn_readlane(__float_as_int(h1), c));
            accz = fmaf(hc, w2[c], accz);
        }
        if (lane < 32) z2[(size_t)i * 32 + lane] = f2bf(accz);
        else           r2[(size_t)i * 32 + (lane - 32)] = accz;
    }
}

// ---------- 4. fused layer-2 agg + epilogue:
// A2 = mean(z2); h2 = relu(A2 + r2); out = h2 . wlin + blin
template <typename TW, typename TOut>
__global__ __launch_bounds__(256) void layer2_final_kernel(
    const u16* __restrict__ z2, const float* __restrict__ r2,
    const int* __restrict__ row_ptr, const int* __restrict__ ssrc,
    const TW* __restrict__ Wlin, const TW* __restrict__ blin,
    TOut* __restrict__ out, const int* __restrict__ flags, int n, int mode)
{
    if (flags[0] != mode) return;
    const int lane = threadIdx.x & 63;
    const int wid = (blockIdx.x * blockDim.x + threadIdx.x) >> 6;
    const int nw = (gridDim.x * blockDim.x) >> 6;
    const int g = lane >> 2;    // 16 edge slots per wave
    const int q = lane & 3;     // feature octet (8 ch)
    float wlin8[8];
    load8(Wlin + q * 8, wlin8);
    const float bl = to_f(blin[0]);
    for (int i = wid; i < n; i += nw) {
        const int rb = row_ptr[i], re = row_ptr[i + 1];
        float acc[8];
        #pragma unroll
        for (int k = 0; k < 8; ++k) acc[k] = 0.f;
        for (int e = rb + g; e < re; e += 16) {
            int s = ssrc[e];
            float v[8];
            load8(z2 + (size_t)s * 32 + q * 8, v);   // one 64B line per edge
            #pragma unroll
            for (int k = 0; k < 8; ++k) acc[k] += v[k];
        }
        #pragma unroll
        for (int m = 4; m < 64; m <<= 1) {
            #pragma unroll
            for (int k = 0; k < 8; ++k) acc[k] += __shfl_xor(acc[k], m, 64);
        }
        float partial = 0.0f;
        if (g == 0) {
            const float inv = 1.0f / (float)max(re - rb, 1);
            float r2v[8];
            load8(r2 + (size_t)i * 32 + q * 8, r2v);
            #pragma unroll
            for (int k = 0; k < 8; ++k)
                partial += fmaxf(fmaf(acc[k], inv, r2v[k]), 0.0f) * wlin8[k];
        }
        partial += __shfl_xor(partial, 1, 64);   // reduce lanes 0..3 (others carry 0)
        partial += __shfl_xor(partial, 2, 64);
        if (lane == 0) out[i] = OutCvt<TOut>::cvt(partial + bl);
    }
}

// ---------- host ----------
extern "C" void kernel_launch(void* const* d_in, const int* in_sizes, int n_in,
                              void* d_out, int out_size, void* d_ws, size_t ws_size,
                              hipStream_t stream) {
    (void)n_in; (void)out_size; (void)ws_size;
    const int N = in_sizes[0] / 64;
    const int E = in_sizes[1] / 2;

    char* ws = (char*)d_ws;
    size_t off = 0;
    auto alloc = [&](size_t bytes) -> void* {
        void* p = ws + off;
        off += (bytes + 255) & ~(size_t)255;
        return p;
    };
    int*   flags   = (int*)alloc(16);
    int*   cnt     = (int*)alloc((size_t)N * 4);
    int*   within  = (int*)alloc((size_t)E * 4);
    int*   row_ptr = (int*)alloc(((size_t)N + 1) * 4);
    int*   ssrc    = (int*)alloc((size_t)E * 4);
    float* A1      = (float*)alloc((size_t)N * 64 * 4);
    u16*   z2      = (u16*)alloc((size_t)N * 32 * 2);
    float* r2      = (float*)alloc((size_t)N * 32 * 4);

    const int* idx = (const int*)d_in[1];
    const int egrid = (E + 255) / 256;

    detect_kernel<<<1, 64, 0, stream>>>((const u16*)d_in[0], (const u32*)d_in[1], flags);
    hipMemsetAsync(cnt, 0, (size_t)N * 4, stream);
    hist_kernel<<<egrid, 256, 0, stream>>>(idx, flags, cnt, within, E);
    scan_kernel<<<1, SCAN_THREADS, 0, stream>>>(cnt, row_ptr, N);
    scatter_kernel<<<egrid, 256, 0, stream>>>(idx, flags, row_ptr, within, ssrc, E);

    // layer-1 aggregation of raw x (mode-guarded dual variants)
    agg_kernel<u16, 64><<<2048, 256, 0, stream>>>((const u16*)d_in[0], row_ptr, ssrc, A1, flags, N, 1);
    agg_kernel<float, 64><<<2048, 256, 0, stream>>>((const float*)d_in[0], row_ptr, ssrc, A1, flags, N, 0);

    layer1_kernel<u16><<<1024, 256, 0, stream>>>(A1, (const u16*)d_in[0],
        (const u16*)d_in[2], (const u16*)d_in[3], (const u16*)d_in[4],
        (const u16*)d_in[5], (const u16*)d_in[6], (const u16*)d_in[7],
        z2, r2, flags, N, 1);
    layer1_kernel<float><<<1024, 256, 0, stream>>>(A1, (const float*)d_in[0],
        (const float*)d_in[2], (const float*)d_in[3], (const float*)d_in[4],
        (const float*)d_in[5], (const float*)d_in[6], (const float*)d_in[7],
        z2, r2, flags, N, 0);

    // fused layer-2 aggregation + final linear
    layer2_final_kernel<u16, u16><<<2048, 256, 0, stream>>>(z2, r2, row_ptr, ssrc,
        (const u16*)d_in[8], (const u16*)d_in[9], (u16*)d_out, flags, N, 1);
    layer2_final_kernel<float, float><<<2048, 256, 0, stream>>>(z2, r2, row_ptr, ssrc,
        (const float*)d_in[8], (const float*)d_in[9], (float*)d_out, flags, N, 0);
}